// Round 1
// baseline (445.698 us; speedup 1.0000x reference)
//
#include <hip/hip_runtime.h>
#include <hip/hip_bf16.h>

// Problem constants
#define N_TOK 8192
#define INL   512
#define OUTL  512
#define NE    8
#define NI    16

typedef unsigned short ushort_t;
typedef unsigned int   uint_t;
typedef short  short8  __attribute__((ext_vector_type(8)));
typedef float  floatx4 __attribute__((ext_vector_type(4)));

// ---------------- workspace layout (bytes) ----------------
// total ~4.6 MB
#define WS_S      0u         // float[512]   : s[h] = sum_n ins[n,h]
#define WS_GAM    2048u      // float[8]     : gam[e]
#define WS_RGAM   2080u      // float[8]     : router_gamma[e]
#define WS_BET    2112u      // float[4096]  : bet_eff[e][d] = bet + gam*b
#define WS_CNT    18496u     // int[8]       : per-expert token counts
#define WS_LIST   18560u     // int[8*8192]  : token lists
#define WS_WL     280704u    // float[8*8192]: per-entry weight rw*gam
#define WS_WT     542848u    // ushort[8*512*512] : W^T bf16, [e][d][l]

__device__ __forceinline__ ushort_t f2bf(float f) {
    uint_t b = __float_as_uint(f);
    return (ushort_t)((b + 0x7FFFu + ((b >> 16) & 1u)) >> 16);   // RNE
}
__device__ __forceinline__ uint_t pack2(float a, float b) {
    return (uint_t)f2bf(a) | ((uint_t)f2bf(b) << 16);
}

// ---------------- K1: s[h], gam[e], rgam[e], zero counters ----------------
__global__ void k_stats(const float* __restrict__ ins,
                        const float* __restrict__ gamma_w,
                        const float* __restrict__ rmod_w,
                        float* __restrict__ wsS, float* __restrict__ wsGam,
                        float* __restrict__ wsRgam, int* __restrict__ cnt) {
    __shared__ float sS[INL];
    __shared__ float pg[64], pr[64];
    int tid = threadIdx.x;
    // s[h] for h = tid and tid+256
    for (int h = tid; h < INL; h += 256) {
        float a = 0.f;
        for (int n = 0; n < NI; ++n) a += ins[n * INL + h];
        sS[h] = a;
        wsS[h] = a;
    }
    __syncthreads();
    if (tid < 64) {
        int e = tid & 7, qq = tid >> 3;
        float g = 0.f, r = 0.f;
        for (int j = 0; j < 64; ++j) {
            int h = qq * 64 + j;
            float sv = sS[h];
            g += sv * gamma_w[e * INL + h];
            r += sv * rmod_w[h * NE + e];
        }
        pg[tid] = g; pr[tid] = r;
    }
    __syncthreads();
    if (tid < NE) {
        float g = 0.f, r = 0.f;
        for (int qq = 0; qq < 8; ++qq) { g += pg[qq * 8 + tid]; r += pr[qq * 8 + tid]; }
        wsGam[tid]  = g * (1.f / NI);
        wsRgam[tid] = r * (1.f / NI);
        cnt[tid] = 0;
    }
}

// ---------------- K2: bet_eff[e][d] = (1/16) sum_h s[h]*beta[e,h,d] + gam[e]*b[e,d] ----
__global__ void k_bet(const float* __restrict__ beta_w,
                      const float* __restrict__ expert_b,
                      const float* __restrict__ wsS,
                      const float* __restrict__ wsGam,
                      float* __restrict__ wsBet) {
    __shared__ float red[256];
    int e = blockIdx.y;
    int dBase = blockIdx.x * 32;
    int tid = threadIdx.x;
    int doff = tid & 31, hq = tid >> 5;   // 8 h-groups of 64
    float a = 0.f;
    for (int j = 0; j < 64; ++j) {
        int h = hq * 64 + j;
        a += wsS[h] * beta_w[(e * INL + h) * OUTL + dBase + doff];
    }
    red[tid] = a;
    __syncthreads();
    if (tid < 32) {
        float t = 0.f;
        for (int k = 0; k < 8; ++k) t += red[k * 32 + tid];
        int d = dBase + tid;
        wsBet[e * OUTL + d] = t * (1.f / NI) + wsGam[e] * expert_b[e * OUTL + d];
    }
}

// ---------------- K3: router (fp32), top-2, out init, expert lists ----------------
__global__ void k_route(const float* __restrict__ x,
                        const float* __restrict__ gate_w,
                        const float* __restrict__ wsGam,
                        const float* __restrict__ wsRgam,
                        const float* __restrict__ wsBet,
                        int* __restrict__ cnt, int* __restrict__ list,
                        float* __restrict__ wl, float* __restrict__ out) {
    __shared__ float gateT[NE * INL];   // 16 KB, [e][l]
    int tid = threadIdx.x;
    for (int i = 0; i < 16; ++i) {
        int f = tid + 256 * i;          // over (l,e)
        float v = gate_w[f];
        int l = f >> 3, e2 = f & 7;
        gateT[e2 * INL + l] = v;
    }
    __syncthreads();

    int w = tid >> 6, lane = tid & 63;
    int t = blockIdx.x * 4 + w;

    float xv[8];
    for (int i = 0; i < 8; ++i) xv[i] = x[t * INL + lane + 64 * i];

    float acc[NE];
    for (int e = 0; e < NE; ++e) acc[e] = 0.f;
    for (int i = 0; i < 8; ++i) {
        float v = xv[i];
        int base = lane + 64 * i;
        for (int e = 0; e < NE; ++e) acc[e] += v * gateT[e * INL + base];
    }
    // wave-wide butterfly sum (all lanes end with full logits)
    for (int e = 0; e < NE; ++e) {
        float a = acc[e];
        for (int off = 32; off >= 1; off >>= 1) a += __shfl_xor(a, off, 64);
        acc[e] = a;
    }
    float logit[NE];
    for (int e = 0; e < NE; ++e) logit[e] = acc[e] + wsRgam[e];

    // top-2, lowest-index tie-break (strict >)
    int i0 = 0; float m0 = logit[0];
    for (int e = 1; e < NE; ++e) if (logit[e] > m0) { m0 = logit[e]; i0 = e; }
    int i1 = -1; float m1 = -3.4e38f;
    for (int e = 0; e < NE; ++e) if (e != i0 && logit[e] > m1) { m1 = logit[e]; i1 = e; }

    float S = 0.f;
    for (int e = 0; e < NE; ++e) S += expf(logit[e] - m0);
    float rw0 = 1.0f / S;                 // exp(0)/S
    float rw1 = expf(m1 - m0) / S;

    if (lane == 0) {
        float w0 = rw0 * wsGam[i0];
        float w1 = rw1 * wsGam[i1];
        int p0 = atomicAdd(&cnt[i0], 1);
        list[i0 * N_TOK + p0] = t; wl[i0 * N_TOK + p0] = w0;
        int p1 = atomicAdd(&cnt[i1], 1);
        list[i1 * N_TOK + p1] = t; wl[i1 * N_TOK + p1] = w1;
    }
    // out init: rw0*bet_eff[i0] + rw1*bet_eff[i1]
    for (int i = 0; i < 8; ++i) {
        int c = lane + 64 * i;
        out[t * OUTL + c] = rw0 * wsBet[i0 * OUTL + c] + rw1 * wsBet[i1 * OUTL + c];
    }
}

// ---------------- K4: W [e][l][d] fp32 -> Wt [e][d][l] bf16 ----------------
__global__ void k_wt(const float* __restrict__ expert_w, ushort_t* __restrict__ wt) {
    __shared__ float tile[64][65];
    int e = blockIdx.z;
    int lt = blockIdx.y * 64, dt = blockIdx.x * 64;
    int tid = threadIdx.x;
    int dIdx = tid & 63, lq = tid >> 6;
    for (int i = 0; i < 16; ++i) {
        int l = lq * 16 + i;
        tile[l][dIdx] = expert_w[(e * INL + lt + l) * OUTL + dt + dIdx];
    }
    __syncthreads();
    int lIdx = tid & 63, dq = tid >> 6;
    for (int i = 0; i < 16; ++i) {
        int d = dq * 16 + i;
        wt[(e * OUTL + dt + d) * INL + lt + lIdx] = f2bf(tile[lIdx][d]);
    }
}

// ---------------- K5: gathered per-expert GEMM, 128x128 tile, BK=64 ----------------
#define LDP 72   // LDS pitch in bf16 elems (64 + 8 pad; 144B, 16B-multiple)
__global__ __launch_bounds__(256, 2)
void k_gemm(const float* __restrict__ x, const ushort_t* __restrict__ wt,
            const int* __restrict__ cnt, const int* __restrict__ list,
            const float* __restrict__ wl, float* __restrict__ out) {
    int rt = blockIdx.x, e = blockIdx.y, ct = blockIdx.z;
    int cnt_e = cnt[e];
    int rowStart = rt * 128;
    if (rowStart >= cnt_e) return;

    __shared__ ushort_t Alds[128 * LDP];
    __shared__ ushort_t Blds[128 * LDP];
    __shared__ int   tokLds[128];
    __shared__ float wLds[128];

    int tid = threadIdx.x;
    if (tid < 128) {
        int grow = rowStart + tid;
        bool v = grow < cnt_e;
        tokLds[tid] = v ? list[e * N_TOK + grow] : 0;
        wLds[tid]   = v ? wl[e * N_TOK + grow] : 0.f;
    }
    __syncthreads();

    int wid = tid >> 6, lane = tid & 63;
    int wm = (wid >> 1) * 64, wn = (wid & 1) * 64;
    int mrow = lane & 15, q8 = (lane >> 4) * 8;

    floatx4 acc[4][4];
    for (int mt = 0; mt < 4; ++mt)
        for (int nt = 0; nt < 4; ++nt)
            acc[mt][nt] = (floatx4){0.f, 0.f, 0.f, 0.f};

    int r = tid >> 1, half = tid & 1;   // staging mapping: 128 rows x 2 halves

    for (int kc = 0; kc < 8; ++kc) {
        int k0 = kc * 64;
        if (kc > 0) __syncthreads();    // protect LDS from overwrite

        // stage A: gathered x rows, fp32 -> bf16
        {
            const float* srcA = x + (size_t)tokLds[r] * INL + k0 + half * 32;
            for (int i = 0; i < 4; ++i) {
                float4 u = *(const float4*)(srcA + i * 8);
                float4 v = *(const float4*)(srcA + i * 8 + 4);
                uint4 wv;
                wv.x = pack2(u.x, u.y); wv.y = pack2(u.z, u.w);
                wv.z = pack2(v.x, v.y); wv.w = pack2(v.z, v.w);
                *(uint4*)&Alds[r * LDP + half * 32 + i * 8] = wv;
            }
        }
        // stage B: Wt[e][ct*128 + c][k0..k0+64), already bf16
        {
            const uint4* srcB = (const uint4*)(wt + ((size_t)(e * OUTL + ct * 128 + r)) * INL + k0 + half * 32);
            for (int i = 0; i < 2; ++i) {
                uint4 wv0 = srcB[i * 2];
                uint4 wv1 = srcB[i * 2 + 1];
                *(uint4*)&Blds[r * LDP + half * 32 + i * 16] = wv0;
                *(uint4*)&Blds[r * LDP + half * 32 + i * 16 + 8] = wv1;
            }
        }
        __syncthreads();

        for (int ks = 0; ks < 64; ks += 32) {
            short8 af[4], bf[4];
            for (int mt = 0; mt < 4; ++mt)
                af[mt] = *(const short8*)&Alds[(wm + mt * 16 + mrow) * LDP + ks + q8];
            for (int nt = 0; nt < 4; ++nt)
                bf[nt] = *(const short8*)&Blds[(wn + nt * 16 + mrow) * LDP + ks + q8];
            for (int mt = 0; mt < 4; ++mt)
                for (int nt = 0; nt < 4; ++nt)
                    acc[mt][nt] = __builtin_amdgcn_mfma_f32_16x16x32_bf16(
                        af[mt], bf[nt], acc[mt][nt], 0, 0, 0);
        }
    }

    // epilogue: out[tok, col] += w * acc   (C/D: col=lane&15, row=(lane>>4)*4+reg)
    int qr = (lane >> 4) * 4;
    for (int mt = 0; mt < 4; ++mt) {
        for (int ri = 0; ri < 3 + 1; ++ri) {
            int lrow = wm + mt * 16 + qr + ri;
            int grow = rowStart + lrow;
            if (grow < cnt_e) {
                int tok = tokLds[lrow];
                float wv = wLds[lrow];
                for (int nt = 0; nt < 4; ++nt) {
                    int col = ct * 128 + wn + nt * 16 + (lane & 15);
                    atomicAdd(&out[(size_t)tok * OUTL + col], wv * acc[mt][nt][ri]);
                }
            }
        }
    }
}

extern "C" void kernel_launch(void* const* d_in, const int* in_sizes, int n_in,
                              void* d_out, int out_size, void* d_ws, size_t ws_size,
                              hipStream_t stream) {
    const float* x        = (const float*)d_in[0];
    const float* ins      = (const float*)d_in[1];
    const float* gate_w   = (const float*)d_in[2];
    const float* expert_w = (const float*)d_in[3];
    const float* expert_b = (const float*)d_in[4];
    const float* gamma_w  = (const float*)d_in[5];
    const float* beta_w   = (const float*)d_in[6];
    const float* rmod_w   = (const float*)d_in[7];
    float* out = (float*)d_out;

    char* ws = (char*)d_ws;
    float*    wsS    = (float*)(ws + WS_S);
    float*    wsGam  = (float*)(ws + WS_GAM);
    float*    wsRgam = (float*)(ws + WS_RGAM);
    float*    wsBet  = (float*)(ws + WS_BET);
    int*      cnt    = (int*)(ws + WS_CNT);
    int*      list   = (int*)(ws + WS_LIST);
    float*    wl     = (float*)(ws + WS_WL);
    ushort_t* wt     = (ushort_t*)(ws + WS_WT);

    // independent: W transpose+convert
    k_wt<<<dim3(8, 8, 8), 256, 0, stream>>>(expert_w, wt);
    // stats -> bet -> route -> gemm (stream-ordered dependencies)
    k_stats<<<1, 256, 0, stream>>>(ins, gamma_w, rmod_w, wsS, wsGam, wsRgam, cnt);
    k_bet<<<dim3(16, 8), 256, 0, stream>>>(beta_w, expert_b, wsS, wsGam, wsBet);
    k_route<<<N_TOK / 4, 256, 0, stream>>>(x, gate_w, wsGam, wsRgam, wsBet, cnt, list, wl, out);
    k_gemm<<<dim3(64, 8, 4), 256, 0, stream>>>(x, wt, cnt, list, wl, out);
}

// Round 2
// 252.712 us; speedup vs baseline: 1.7637x; 1.7637x over previous
//
#include <hip/hip_runtime.h>
#include <hip/hip_bf16.h>
#include <hip/hip_fp16.h>

// Problem constants
#define N_TOK 8192
#define INL   512
#define OUTL  512
#define NE    8
#define NI    16

typedef unsigned short ushort_t;
typedef unsigned int   uint_t;
typedef short  short8  __attribute__((ext_vector_type(8)));
typedef float  floatx4 __attribute__((ext_vector_type(4)));

// ---------------- workspace layout (bytes), total ~4.59 MB ----------------
#define WS_S      0u         // float[512]    : s[h] = sum_n ins[n,h]
#define WS_GAM    2048u      // float[8]      : gam[e]
#define WS_RGAM   2080u      // float[8]      : router_gamma[e]
#define WS_BET    2112u      // float[4096]   : bet_eff[e][d] = bet + gam*b
#define WS_CNT    18496u     // int[16*64]    : per-(slot,expert) counts, 256B-strided
#define WS_SEL    22592u     // int2[8192]    : per-token packed (e<<16|fp16(w)) x2
#define WS_LIST   88128u     // int[16*8192]  : per-bin entries (tok<<16|fp16(w))
#define WS_WT     612416u    // ushort[8*512*512] : W^T bf16, [e][d][l]

__device__ __forceinline__ ushort_t f2bf(float f) {
    uint_t b = __float_as_uint(f);
    return (ushort_t)((b + 0x7FFFu + ((b >> 16) & 1u)) >> 16);   // RNE
}
__device__ __forceinline__ uint_t pack2(float a, float b) {
    return (uint_t)f2bf(a) | ((uint_t)f2bf(b) << 16);
}

// ---------------- K1: s[h], gam[e], rgam[e], zero counters ----------------
__global__ void k_stats(const float* __restrict__ ins,
                        const float* __restrict__ gamma_w,
                        const float* __restrict__ rmod_w,
                        float* __restrict__ wsS, float* __restrict__ wsGam,
                        float* __restrict__ wsRgam, int* __restrict__ cnt) {
    __shared__ float sS[INL];
    __shared__ float pg[64], pr[64];
    int tid = threadIdx.x;
    for (int h = tid; h < INL; h += 256) {
        float a = 0.f;
        for (int n = 0; n < NI; ++n) a += ins[n * INL + h];
        sS[h] = a;
        wsS[h] = a;
    }
    __syncthreads();
    if (tid < 64) {
        int e = tid & 7, qq = tid >> 3;
        float g = 0.f, r = 0.f;
        for (int j = 0; j < 64; ++j) {
            int h = qq * 64 + j;
            float sv = sS[h];
            g += sv * gamma_w[e * INL + h];
            r += sv * rmod_w[h * NE + e];
        }
        pg[tid] = g; pr[tid] = r;
    }
    __syncthreads();
    if (tid < 16) cnt[tid * 64] = 0;     // strided counters, one line per bin
    if (tid < NE) {
        float g = 0.f, r = 0.f;
        for (int qq = 0; qq < 8; ++qq) { g += pg[qq * 8 + tid]; r += pr[qq * 8 + tid]; }
        wsGam[tid]  = g * (1.f / NI);
        wsRgam[tid] = r * (1.f / NI);
    }
}

// ---------------- K2: bet_eff[e][d] = (1/16) sum_h s[h]*beta[e,h,d] + gam[e]*b[e,d] ----
__global__ void k_bet(const float* __restrict__ beta_w,
                      const float* __restrict__ expert_b,
                      const float* __restrict__ wsS,
                      const float* __restrict__ wsGam,
                      float* __restrict__ wsBet) {
    __shared__ float red[256];
    int e = blockIdx.y;
    int dBase = blockIdx.x * 32;
    int tid = threadIdx.x;
    int doff = tid & 31, hq = tid >> 5;
    float a = 0.f;
    for (int j = 0; j < 64; ++j) {
        int h = hq * 64 + j;
        a += wsS[h] * beta_w[(e * INL + h) * OUTL + dBase + doff];
    }
    red[tid] = a;
    __syncthreads();
    if (tid < 32) {
        float t = 0.f;
        for (int k = 0; k < 8; ++k) t += red[k * 32 + tid];
        int d = dBase + tid;
        wsBet[e * OUTL + d] = t * (1.f / NI) + wsGam[e] * expert_b[e * OUTL + d];
    }
}

// ---------------- K3: router (fp32), top-2, out init. NO atomics. ----------------
__global__ void k_route(const float* __restrict__ x,
                        const float* __restrict__ gate_w,
                        const float* __restrict__ wsGam,
                        const float* __restrict__ wsRgam,
                        const float* __restrict__ wsBet,
                        int2* __restrict__ selw, float* __restrict__ out) {
    __shared__ float gateT[NE * INL];   // 16 KB, [e][l]
    int tid = threadIdx.x;
    for (int i = 0; i < 16; ++i) {
        int f = tid + 256 * i;
        float v = gate_w[f];
        int l = f >> 3, e2 = f & 7;
        gateT[e2 * INL + l] = v;
    }
    __syncthreads();

    int w = tid >> 6, lane = tid & 63;
    int t = blockIdx.x * 4 + w;

    float xv[8];
    for (int i = 0; i < 8; ++i) xv[i] = x[t * INL + lane + 64 * i];

    float acc[NE];
    for (int e = 0; e < NE; ++e) acc[e] = 0.f;
    for (int i = 0; i < 8; ++i) {
        float v = xv[i];
        int base = lane + 64 * i;
        for (int e = 0; e < NE; ++e) acc[e] += v * gateT[e * INL + base];
    }
    for (int e = 0; e < NE; ++e) {
        float a = acc[e];
        for (int off = 32; off >= 1; off >>= 1) a += __shfl_xor(a, off, 64);
        acc[e] = a;
    }
    float logit[NE];
    for (int e = 0; e < NE; ++e) logit[e] = acc[e] + wsRgam[e];

    // top-2, lowest-index tie-break (strict >)
    int i0 = 0; float m0 = logit[0];
    for (int e = 1; e < NE; ++e) if (logit[e] > m0) { m0 = logit[e]; i0 = e; }
    int i1 = -1; float m1 = -3.4e38f;
    for (int e = 0; e < NE; ++e) if (e != i0 && logit[e] > m1) { m1 = logit[e]; i1 = e; }

    float S = 0.f;
    for (int e = 0; e < NE; ++e) S += expf(logit[e] - m0);
    float rw0 = 1.0f / S;
    float rw1 = expf(m1 - m0) / S;

    if (lane == 0) {
        uint_t u0 = ((uint_t)i0 << 16) | (uint_t)__half_as_ushort(__float2half(rw0 * wsGam[i0]));
        uint_t u1 = ((uint_t)i1 << 16) | (uint_t)__half_as_ushort(__float2half(rw1 * wsGam[i1]));
        selw[t] = make_int2((int)u0, (int)u1);
    }
    for (int i = 0; i < 8; ++i) {
        int c = lane + 64 * i;
        out[t * OUTL + c] = rw0 * wsBet[i0 * OUTL + c] + rw1 * wsBet[i1 * OUTL + c];
    }
}

// ---------------- K3b: build per-(slot,expert) lists. 64 blocks x 128 thr. ----------
__global__ void k_scatter(const int2* __restrict__ selw,
                          int* __restrict__ cnt, int* __restrict__ list) {
    __shared__ int lcnt[16], lbase[16];
    int tid = threadIdx.x;
    if (tid < 16) lcnt[tid] = 0;
    __syncthreads();
    int t = blockIdx.x * 128 + tid;
    int2 sw = selw[t];
    uint_t u0 = (uint_t)sw.x, u1 = (uint_t)sw.y;
    int binA = (int)(u0 >> 16);          // slot0: bins 0..7
    int binB = 8 + (int)(u1 >> 16);      // slot1: bins 8..15
    int sA = atomicAdd(&lcnt[binA], 1);
    int sB = atomicAdd(&lcnt[binB], 1);
    __syncthreads();
    if (tid < 16) lbase[tid] = atomicAdd(&cnt[tid * 64], lcnt[tid]);
    __syncthreads();
    list[binA * N_TOK + lbase[binA] + sA] = (t << 16) | (int)(u0 & 0xFFFFu);
    list[binB * N_TOK + lbase[binB] + sB] = (t << 16) | (int)(u1 & 0xFFFFu);
}

// ---------------- K4: W [e][l][d] fp32 -> Wt [e][d][l] bf16 ----------------
__global__ void k_wt(const float* __restrict__ expert_w, ushort_t* __restrict__ wt) {
    __shared__ float tile[64][65];
    int e = blockIdx.z;
    int lt = blockIdx.y * 64, dt = blockIdx.x * 64;
    int tid = threadIdx.x;
    int dIdx = tid & 63, lq = tid >> 6;
    for (int i = 0; i < 16; ++i) {
        int l = lq * 16 + i;
        tile[l][dIdx] = expert_w[(e * INL + lt + l) * OUTL + dt + dIdx];
    }
    __syncthreads();
    int lIdx = tid & 63, dq = tid >> 6;
    for (int i = 0; i < 16; ++i) {
        int d = dq * 16 + i;
        wt[(e * OUTL + dt + d) * INL + lt + lIdx] = f2bf(tile[lIdx][d]);
    }
}

// ---------------- K5: gathered per-expert GEMM, 128x128 tile, BK=64 ----------------
// One pass per slot (slotbase = 0 or 8): each token appears exactly once per pass,
// so the epilogue does a plain (non-atomic) load-add-store on out.
#define LDP 72   // LDS pitch in bf16 elems
__global__ __launch_bounds__(256, 2)
void k_gemm(const float* __restrict__ x, const ushort_t* __restrict__ wt,
            const int* __restrict__ cnt, const int* __restrict__ list,
            float* __restrict__ out, int slotbase) {
    int rt = blockIdx.x, e = blockIdx.y, ct = blockIdx.z;
    int bin = slotbase + e;
    int cnt_e = cnt[bin * 64];
    int rowStart = rt * 128;
    if (rowStart >= cnt_e) return;

    __shared__ ushort_t Alds[128 * LDP];
    __shared__ ushort_t Blds[128 * LDP];
    __shared__ int   tokLds[128];
    __shared__ float wLds[128];

    int tid = threadIdx.x;
    if (tid < 128) {
        int grow = rowStart + tid;
        bool v = grow < cnt_e;
        int entry = v ? list[bin * N_TOK + grow] : 0;
        tokLds[tid] = (int)((uint_t)entry >> 16);
        wLds[tid]   = v ? __half2float(__ushort_as_half((ushort_t)(entry & 0xFFFF))) : 0.f;
    }
    __syncthreads();

    int wid = tid >> 6, lane = tid & 63;
    int wm = (wid >> 1) * 64, wn = (wid & 1) * 64;
    int mrow = lane & 15, q8 = (lane >> 4) * 8;

    floatx4 acc[4][4];
    for (int mt = 0; mt < 4; ++mt)
        for (int nt = 0; nt < 4; ++nt)
            acc[mt][nt] = (floatx4){0.f, 0.f, 0.f, 0.f};

    int r = tid >> 1, half = tid & 1;

    for (int kc = 0; kc < 8; ++kc) {
        int k0 = kc * 64;
        if (kc > 0) __syncthreads();

        // stage A: gathered x rows, fp32 -> bf16
        {
            const float* srcA = x + (size_t)tokLds[r] * INL + k0 + half * 32;
            for (int i = 0; i < 4; ++i) {
                float4 u = *(const float4*)(srcA + i * 8);
                float4 v = *(const float4*)(srcA + i * 8 + 4);
                uint4 wv;
                wv.x = pack2(u.x, u.y); wv.y = pack2(u.z, u.w);
                wv.z = pack2(v.x, v.y); wv.w = pack2(v.z, v.w);
                *(uint4*)&Alds[r * LDP + half * 32 + i * 8] = wv;
            }
        }
        // stage B: Wt[e][ct*128 + c][k0..k0+64), already bf16
        {
            const uint4* srcB = (const uint4*)(wt + ((size_t)(e * OUTL + ct * 128 + r)) * INL + k0 + half * 32);
            for (int i = 0; i < 2; ++i) {
                uint4 wv0 = srcB[i * 2];
                uint4 wv1 = srcB[i * 2 + 1];
                *(uint4*)&Blds[r * LDP + half * 32 + i * 16] = wv0;
                *(uint4*)&Blds[r * LDP + half * 32 + i * 16 + 8] = wv1;
            }
        }
        __syncthreads();

        for (int ks = 0; ks < 64; ks += 32) {
            short8 af[4], bf[4];
            for (int mt = 0; mt < 4; ++mt)
                af[mt] = *(const short8*)&Alds[(wm + mt * 16 + mrow) * LDP + ks + q8];
            for (int nt = 0; nt < 4; ++nt)
                bf[nt] = *(const short8*)&Blds[(wn + nt * 16 + mrow) * LDP + ks + q8];
            for (int mt = 0; mt < 4; ++mt)
                for (int nt = 0; nt < 4; ++nt)
                    acc[mt][nt] = __builtin_amdgcn_mfma_f32_16x16x32_bf16(
                        af[mt], bf[nt], acc[mt][nt], 0, 0, 0);
        }
    }

    // epilogue: out[tok, col] += w * acc   (plain RMW; exclusive per pass)
    int qr = (lane >> 4) * 4;
    for (int mt = 0; mt < 4; ++mt) {
        for (int ri = 0; ri < 4; ++ri) {
            int lrow = wm + mt * 16 + qr + ri;
            int grow = rowStart + lrow;
            if (grow < cnt_e) {
                int tok = tokLds[lrow];
                float wv = wLds[lrow];
                for (int nt = 0; nt < 4; ++nt) {
                    int col = ct * 128 + wn + nt * 16 + (lane & 15);
                    size_t idx = (size_t)tok * OUTL + col;
                    out[idx] += wv * acc[mt][nt][ri];
                }
            }
        }
    }
}

extern "C" void kernel_launch(void* const* d_in, const int* in_sizes, int n_in,
                              void* d_out, int out_size, void* d_ws, size_t ws_size,
                              hipStream_t stream) {
    const float* x        = (const float*)d_in[0];
    const float* ins      = (const float*)d_in[1];
    const float* gate_w   = (const float*)d_in[2];
    const float* expert_w = (const float*)d_in[3];
    const float* expert_b = (const float*)d_in[4];
    const float* gamma_w  = (const float*)d_in[5];
    const float* beta_w   = (const float*)d_in[6];
    const float* rmod_w   = (const float*)d_in[7];
    float* out = (float*)d_out;

    char* ws = (char*)d_ws;
    float*    wsS    = (float*)(ws + WS_S);
    float*    wsGam  = (float*)(ws + WS_GAM);
    float*    wsRgam = (float*)(ws + WS_RGAM);
    float*    wsBet  = (float*)(ws + WS_BET);
    int*      cnt    = (int*)(ws + WS_CNT);
    int2*     selw   = (int2*)(ws + WS_SEL);
    int*      list   = (int*)(ws + WS_LIST);
    ushort_t* wt     = (ushort_t*)(ws + WS_WT);

    // independent: W transpose+convert
    k_wt<<<dim3(8, 8, 8), 256, 0, stream>>>(expert_w, wt);
    // stats -> bet -> route -> scatter -> gemm (stream-ordered dependencies)
    k_stats<<<1, 256, 0, stream>>>(ins, gamma_w, rmod_w, wsS, wsGam, wsRgam, cnt);
    k_bet<<<dim3(16, 8), 256, 0, stream>>>(beta_w, expert_b, wsS, wsGam, wsBet);
    k_route<<<N_TOK / 4, 256, 0, stream>>>(x, gate_w, wsGam, wsRgam, wsBet, selw, out);
    k_scatter<<<N_TOK / 128, 128, 0, stream>>>(selw, cnt, list);
    k_gemm<<<dim3(64, 8, 4), 256, 0, stream>>>(x, wt, cnt, list, out, 0);
    k_gemm<<<dim3(64, 8, 4), 256, 0, stream>>>(x, wt, cnt, list, out, 8);
}

// Round 3
// 240.940 us; speedup vs baseline: 1.8498x; 1.0489x over previous
//
#include <hip/hip_runtime.h>
#include <hip/hip_bf16.h>
#include <hip/hip_fp16.h>

// Problem constants
#define N_TOK 8192
#define INL   512
#define OUTL  512
#define NE    8
#define NI    16

typedef unsigned short ushort_t;
typedef unsigned int   uint_t;
typedef short  short8  __attribute__((ext_vector_type(8)));
typedef float  floatx4 __attribute__((ext_vector_type(4)));

// ---------------- workspace layout (bytes), total ~4.59 MB ----------------
#define WS_S      0u         // float[512]    : s[h] = sum_n ins[n,h]
#define WS_GAM    2048u      // float[8]      : gam[e]
#define WS_RGAM   2080u      // float[8]      : router_gamma[e]
#define WS_BET    2112u      // float[4096]   : bet_eff[e][d] = bet + gam*b
#define WS_CNT    18496u     // int[16*64]    : per-(slot,expert) counts, 256B-strided
#define WS_SEL    22592u     // int2[8192]    : per-token packed (e<<16|fp16(w)) x2
#define WS_LIST   88128u     // int[16*8192]  : per-bin entries (tok<<16|fp16(w))
#define WS_WT     612416u    // ushort[8*512*512] : W^T bf16, [e][d][l]

__device__ __forceinline__ ushort_t f2bf(float f) {
    uint_t b = __float_as_uint(f);
    return (ushort_t)((b + 0x7FFFu + ((b >> 16) & 1u)) >> 16);   // RNE
}
__device__ __forceinline__ uint_t pack2(float a, float b) {
    return (uint_t)f2bf(a) | ((uint_t)f2bf(b) << 16);
}

// ---------------- K1: s[h], gam[e], rgam[e], zero counters ----------------
__global__ void k_stats(const float* __restrict__ ins,
                        const float* __restrict__ gamma_w,
                        const float* __restrict__ rmod_w,
                        float* __restrict__ wsS, float* __restrict__ wsGam,
                        float* __restrict__ wsRgam, int* __restrict__ cnt) {
    __shared__ float sS[INL];
    __shared__ float pg[64], pr[64];
    int tid = threadIdx.x;
    for (int h = tid; h < INL; h += 256) {
        float a = 0.f;
        for (int n = 0; n < NI; ++n) a += ins[n * INL + h];
        sS[h] = a;
        wsS[h] = a;
    }
    __syncthreads();
    if (tid < 64) {
        int e = tid & 7, qq = tid >> 3;
        float g = 0.f, r = 0.f;
        for (int j = 0; j < 64; ++j) {
            int h = qq * 64 + j;
            float sv = sS[h];
            g += sv * gamma_w[e * INL + h];
            r += sv * rmod_w[h * NE + e];
        }
        pg[tid] = g; pr[tid] = r;
    }
    __syncthreads();
    if (tid < 16) cnt[tid * 64] = 0;     // strided counters, one line per bin
    if (tid < NE) {
        float g = 0.f, r = 0.f;
        for (int qq = 0; qq < 8; ++qq) { g += pg[qq * 8 + tid]; r += pr[qq * 8 + tid]; }
        wsGam[tid]  = g * (1.f / NI);
        wsRgam[tid] = r * (1.f / NI);
    }
}

// ---------------- K2: bet_eff[e][d] = (1/16) sum_h s[h]*beta[e,h,d] + gam[e]*b[e,d] ----
__global__ void k_bet(const float* __restrict__ beta_w,
                      const float* __restrict__ expert_b,
                      const float* __restrict__ wsS,
                      const float* __restrict__ wsGam,
                      float* __restrict__ wsBet) {
    __shared__ float red[256];
    int e = blockIdx.y;
    int dBase = blockIdx.x * 32;
    int tid = threadIdx.x;
    int doff = tid & 31, hq = tid >> 5;
    float a = 0.f;
    for (int j = 0; j < 64; ++j) {
        int h = hq * 64 + j;
        a += wsS[h] * beta_w[(e * INL + h) * OUTL + dBase + doff];
    }
    red[tid] = a;
    __syncthreads();
    if (tid < 32) {
        float t = 0.f;
        for (int k = 0; k < 8; ++k) t += red[k * 32 + tid];
        int d = dBase + tid;
        wsBet[e * OUTL + d] = t * (1.f / NI) + wsGam[e] * expert_b[e * OUTL + d];
    }
}

// ---------------- K3: router (fp32), top-2, out init. NO atomics. ----------------
__global__ void k_route(const float* __restrict__ x,
                        const float* __restrict__ gate_w,
                        const float* __restrict__ wsGam,
                        const float* __restrict__ wsRgam,
                        const float* __restrict__ wsBet,
                        int2* __restrict__ selw, float* __restrict__ out) {
    __shared__ float gateT[NE * INL];   // 16 KB, [e][l]
    int tid = threadIdx.x;
    for (int i = 0; i < 16; ++i) {
        int f = tid + 256 * i;
        float v = gate_w[f];
        int l = f >> 3, e2 = f & 7;
        gateT[e2 * INL + l] = v;
    }
    __syncthreads();

    int w = tid >> 6, lane = tid & 63;
    int t = blockIdx.x * 4 + w;

    float xv[8];
    for (int i = 0; i < 8; ++i) xv[i] = x[t * INL + lane + 64 * i];

    float acc[NE];
    for (int e = 0; e < NE; ++e) acc[e] = 0.f;
    for (int i = 0; i < 8; ++i) {
        float v = xv[i];
        int base = lane + 64 * i;
        for (int e = 0; e < NE; ++e) acc[e] += v * gateT[e * INL + base];
    }
    for (int e = 0; e < NE; ++e) {
        float a = acc[e];
        for (int off = 32; off >= 1; off >>= 1) a += __shfl_xor(a, off, 64);
        acc[e] = a;
    }
    float logit[NE];
    for (int e = 0; e < NE; ++e) logit[e] = acc[e] + wsRgam[e];

    // top-2, lowest-index tie-break (strict >)
    int i0 = 0; float m0 = logit[0];
    for (int e = 1; e < NE; ++e) if (logit[e] > m0) { m0 = logit[e]; i0 = e; }
    int i1 = -1; float m1 = -3.4e38f;
    for (int e = 0; e < NE; ++e) if (e != i0 && logit[e] > m1) { m1 = logit[e]; i1 = e; }

    float S = 0.f;
    for (int e = 0; e < NE; ++e) S += expf(logit[e] - m0);
    float rw0 = 1.0f / S;
    float rw1 = expf(m1 - m0) / S;

    if (lane == 0) {
        uint_t u0 = ((uint_t)i0 << 16) | (uint_t)__half_as_ushort(__float2half(rw0 * wsGam[i0]));
        uint_t u1 = ((uint_t)i1 << 16) | (uint_t)__half_as_ushort(__float2half(rw1 * wsGam[i1]));
        selw[t] = make_int2((int)u0, (int)u1);
    }
    for (int i = 0; i < 8; ++i) {
        int c = lane + 64 * i;
        out[t * OUTL + c] = rw0 * wsBet[i0 * OUTL + c] + rw1 * wsBet[i1 * OUTL + c];
    }
}

// ---------------- K3b: build per-(slot,expert) lists. 64 blocks x 128 thr. ----------
__global__ void k_scatter(const int2* __restrict__ selw,
                          int* __restrict__ cnt, int* __restrict__ list) {
    __shared__ int lcnt[16], lbase[16];
    int tid = threadIdx.x;
    if (tid < 16) lcnt[tid] = 0;
    __syncthreads();
    int t = blockIdx.x * 128 + tid;
    int2 sw = selw[t];
    uint_t u0 = (uint_t)sw.x, u1 = (uint_t)sw.y;
    int binA = (int)(u0 >> 16);          // slot0: bins 0..7
    int binB = 8 + (int)(u1 >> 16);      // slot1: bins 8..15
    int sA = atomicAdd(&lcnt[binA], 1);
    int sB = atomicAdd(&lcnt[binB], 1);
    __syncthreads();
    if (tid < 16) lbase[tid] = atomicAdd(&cnt[tid * 64], lcnt[tid]);
    __syncthreads();
    list[binA * N_TOK + lbase[binA] + sA] = (t << 16) | (int)(u0 & 0xFFFFu);
    list[binB * N_TOK + lbase[binB] + sB] = (t << 16) | (int)(u1 & 0xFFFFu);
}

// ---------------- K4: W [e][l][d] fp32 -> Wt [e][d][l] bf16 ----------------
__global__ void k_wt(const float* __restrict__ expert_w, ushort_t* __restrict__ wt) {
    __shared__ float tile[64][65];
    int e = blockIdx.z;
    int lt = blockIdx.y * 64, dt = blockIdx.x * 64;
    int tid = threadIdx.x;
    int dIdx = tid & 63, lq = tid >> 6;
    for (int i = 0; i < 16; ++i) {
        int l = lq * 16 + i;
        tile[l][dIdx] = expert_w[(e * INL + lt + l) * OUTL + dt + dIdx];
    }
    __syncthreads();
    int lIdx = tid & 63, dq = tid >> 6;
    for (int i = 0; i < 16; ++i) {
        int d = dq * 16 + i;
        wt[(e * OUTL + dt + d) * INL + lt + lIdx] = f2bf(tile[lIdx][d]);
    }
}

// ---------------- K5: fused gathered GEMM over 16 (slot,expert) bins ----------------
// M=64 x N=128 tile, BK=64, register-prefetch double buffer.
// ~1024 working blocks -> ~4 blocks/CU resident for latency hiding.
// Epilogue atomicAdd (slot0/slot1 blocks of the same token may run concurrently).
#define LDP 72   // LDS pitch in bf16 elems
__global__ __launch_bounds__(256, 4)
void k_gemm(const float* __restrict__ x, const ushort_t* __restrict__ wt,
            const int* __restrict__ cnt, const int* __restrict__ list,
            float* __restrict__ out) {
    int rt = blockIdx.x;                 // 0..31 row tiles (loop if bin larger)
    int bin = blockIdx.y;                // 0..15 (slot*8 + e)
    int ct = blockIdx.z;                 // 0..3 column tiles of 128
    int e = bin & 7;
    int cnt_e = cnt[bin * 64];
    if (rt * 64 >= cnt_e) return;

    __shared__ ushort_t Alds[64 * LDP];     // 9.2 KB
    __shared__ ushort_t Blds[128 * LDP];    // 18.4 KB
    __shared__ int   tokLds[64];
    __shared__ float wLds[64];

    int tid = threadIdx.x;
    int wid = tid >> 6, lane = tid & 63;
    int wm = (wid >> 1) * 32, wn = (wid & 1) * 64;
    int mrow = lane & 15, q8 = (lane >> 4) * 8;

    // staging maps
    int ar = tid >> 2, ac = (tid & 3) * 16;       // A: row 0..63, 16 floats each
    int br = tid >> 1, bc = (tid & 1) * 32;       // B: row 0..127, 32 bf16 each
    const ushort_t* wbase = wt + ((size_t)(e * OUTL + ct * 128 + br)) * INL + bc;

    for (int rowStart = rt * 64; rowStart < cnt_e; rowStart += 32 * 64) {
        __syncthreads();                 // protect tok/w + LDS reuse across row-loop iters
        if (tid < 64) {
            int grow = rowStart + tid;
            bool v = grow < cnt_e;
            int entry = v ? list[bin * N_TOK + grow] : 0;
            tokLds[tid] = (int)((uint_t)entry >> 16);
            wLds[tid]   = v ? __half2float(__ushort_as_half((ushort_t)(entry & 0xFFFF))) : 0.f;
        }
        __syncthreads();

        floatx4 acc[2][4];
        for (int mt = 0; mt < 2; ++mt)
            for (int nt = 0; nt < 4; ++nt)
                acc[mt][nt] = (floatx4){0.f, 0.f, 0.f, 0.f};

        const float* srcA = x + (size_t)tokLds[ar] * INL + ac;

        // prefetch tile kc=0
        float4 pa[4];
        uint4  pb[4];
        for (int i = 0; i < 4; ++i) pa[i] = *(const float4*)(srcA + i * 4);
        for (int i = 0; i < 4; ++i) pb[i] = *(const uint4*)(wbase + i * 8);

        for (int kc = 0; kc < 8; ++kc) {
            if (kc > 0) __syncthreads();     // all frag reads of kc-1 done
            // store prefetched tile to LDS (convert A fp32->bf16)
            {
                uint4 w0, w1;
                w0.x = pack2(pa[0].x, pa[0].y); w0.y = pack2(pa[0].z, pa[0].w);
                w0.z = pack2(pa[1].x, pa[1].y); w0.w = pack2(pa[1].z, pa[1].w);
                w1.x = pack2(pa[2].x, pa[2].y); w1.y = pack2(pa[2].z, pa[2].w);
                w1.z = pack2(pa[3].x, pa[3].y); w1.w = pack2(pa[3].z, pa[3].w);
                *(uint4*)&Alds[ar * LDP + ac] = w0;
                *(uint4*)&Alds[ar * LDP + ac + 8] = w1;
                *(uint4*)&Blds[br * LDP + bc]      = pb[0];
                *(uint4*)&Blds[br * LDP + bc + 8]  = pb[1];
                *(uint4*)&Blds[br * LDP + bc + 16] = pb[2];
                *(uint4*)&Blds[br * LDP + bc + 24] = pb[3];
            }
            __syncthreads();
            // issue prefetch for kc+1 (flies during ds_read+MFMA below)
            if (kc < 7) {
                int k0 = (kc + 1) * 64;
                for (int i = 0; i < 4; ++i) pa[i] = *(const float4*)(srcA + k0 + i * 4);
                for (int i = 0; i < 4; ++i) pb[i] = *(const uint4*)(wbase + k0 + i * 8);
            }
            // compute tile kc
            for (int ks = 0; ks < 64; ks += 32) {
                short8 af[2], bf[4];
                for (int mt = 0; mt < 2; ++mt)
                    af[mt] = *(const short8*)&Alds[(wm + mt * 16 + mrow) * LDP + ks + q8];
                for (int nt = 0; nt < 4; ++nt)
                    bf[nt] = *(const short8*)&Blds[(wn + nt * 16 + mrow) * LDP + ks + q8];
                for (int mt = 0; mt < 2; ++mt)
                    for (int nt = 0; nt < 4; ++nt)
                        acc[mt][nt] = __builtin_amdgcn_mfma_f32_16x16x32_bf16(
                            af[mt], bf[nt], acc[mt][nt], 0, 0, 0);
            }
        }

        // epilogue: out[tok, col] += w * acc  (atomic: other slot may race)
        int qr = (lane >> 4) * 4;
        for (int mt = 0; mt < 2; ++mt) {
            for (int ri = 0; ri < 4; ++ri) {
                int lrow = wm + mt * 16 + qr + ri;
                int grow = rowStart + lrow;
                if (grow < cnt_e) {
                    int tok = tokLds[lrow];
                    float wv = wLds[lrow];
                    for (int nt = 0; nt < 4; ++nt) {
                        int col = ct * 128 + wn + nt * 16 + (lane & 15);
                        atomicAdd(&out[(size_t)tok * OUTL + col], wv * acc[mt][nt][ri]);
                    }
                }
            }
        }
    }
}

extern "C" void kernel_launch(void* const* d_in, const int* in_sizes, int n_in,
                              void* d_out, int out_size, void* d_ws, size_t ws_size,
                              hipStream_t stream) {
    const float* x        = (const float*)d_in[0];
    const float* ins      = (const float*)d_in[1];
    const float* gate_w   = (const float*)d_in[2];
    const float* expert_w = (const float*)d_in[3];
    const float* expert_b = (const float*)d_in[4];
    const float* gamma_w  = (const float*)d_in[5];
    const float* beta_w   = (const float*)d_in[6];
    const float* rmod_w   = (const float*)d_in[7];
    float* out = (float*)d_out;

    char* ws = (char*)d_ws;
    float*    wsS    = (float*)(ws + WS_S);
    float*    wsGam  = (float*)(ws + WS_GAM);
    float*    wsRgam = (float*)(ws + WS_RGAM);
    float*    wsBet  = (float*)(ws + WS_BET);
    int*      cnt    = (int*)(ws + WS_CNT);
    int2*     selw   = (int2*)(ws + WS_SEL);
    int*      list   = (int*)(ws + WS_LIST);
    ushort_t* wt     = (ushort_t*)(ws + WS_WT);

    // independent: W transpose+convert
    k_wt<<<dim3(8, 8, 8), 256, 0, stream>>>(expert_w, wt);
    // stats -> bet -> route -> scatter -> gemm (stream-ordered dependencies)
    k_stats<<<1, 256, 0, stream>>>(ins, gamma_w, rmod_w, wsS, wsGam, wsRgam, cnt);
    k_bet<<<dim3(16, 8), 256, 0, stream>>>(beta_w, expert_b, wsS, wsGam, wsBet);
    k_route<<<N_TOK / 4, 256, 0, stream>>>(x, gate_w, wsGam, wsRgam, wsBet, selw, out);
    k_scatter<<<N_TOK / 128, 128, 0, stream>>>(selw, cnt, list);
    k_gemm<<<dim3(32, 16, 4), 256, 0, stream>>>(x, wt, cnt, list, out);
}